// Round 5
// baseline (358.479 us; speedup 1.0000x reference)
//
#include <hip/hip_runtime.h>
#include <stdint.h>

#define HEADS 16
#define HDIM  64
#define NDIM  1024
#define BATCH 4
#define SEQ   2048
#define MTOT  (BATCH * SEQ)   // 8192

typedef __attribute__((ext_vector_type(8))) short short8;
typedef __attribute__((ext_vector_type(4))) float float4v;
typedef __attribute__((ext_vector_type(4))) int int4v;
typedef __attribute__((ext_vector_type(2))) int int2v;
typedef __attribute__((ext_vector_type(4))) unsigned short ushort4v;

static __device__ __forceinline__ unsigned int fbits(float f) {
    union { float f; unsigned int u; } v; v.f = f; return v.u;
}
static __device__ __forceinline__ unsigned short bf16r(float f) {
    return (unsigned short)((fbits(f) + 0x8000u) >> 16);
}
static __device__ __forceinline__ unsigned int pack2(float lo, float hi) {
    return ((fbits(hi) + 0x8000u) & 0xffff0000u) | ((fbits(lo) + 0x8000u) >> 16);
}
// two f32 -> packed bf16x2 in one VALU op (T12 primitive).
static __device__ __forceinline__ unsigned int cvt_pk_bf16(float lo, float hi) {
    unsigned int r;
    asm("v_cvt_pk_bf16_f32 %0, %1, %2" : "=v"(r) : "v"(lo), "v"(hi));
    return r;
}

// async 16B global->LDS (m97 pattern)
static __device__ __forceinline__ void gl_lds16(const unsigned short* g, unsigned short* l) {
    __builtin_amdgcn_global_load_lds(
        (const __attribute__((address_space(1))) unsigned int*)(uintptr_t)g,
        (__attribute__((address_space(3))) unsigned int*)(uintptr_t)l,
        16, 0, 0);
}

// ---------- Kernel 0: cast X fp32 -> bf16 (contiguous) ----------
__global__ __launch_bounds__(256) void cast_x(
    const float* __restrict__ X0, const float* __restrict__ X1, const float* __restrict__ X2,
    unsigned short* __restrict__ Y0, unsigned short* __restrict__ Y1, unsigned short* __restrict__ Y2)
{
    int z = blockIdx.z;
    const float* X = (z == 0) ? X0 : (z == 1) ? X1 : X2;
    unsigned short* Y = (z == 0) ? Y0 : (z == 1) ? Y1 : Y2;
    size_t i = ((size_t)blockIdx.x * 256 + threadIdx.x) * 8;
    float4v a = *(const float4v*)(X + i);
    float4v b = *(const float4v*)(X + i + 4);
    int4v p;
    p.x = pack2(a.x, a.y); p.y = pack2(a.z, a.w);
    p.z = pack2(b.x, b.y); p.w = pack2(b.z, b.w);
    *(int4v*)(Y + i) = p;
}

// ---------- Kernel 1: Wt[n][k] = bf16(W[k][n]) ----------
__global__ __launch_bounds__(256) void cast_transpose_w(
    const float* __restrict__ W0, const float* __restrict__ W1, const float* __restrict__ W2,
    unsigned short* __restrict__ T0, unsigned short* __restrict__ T1, unsigned short* __restrict__ T2)
{
    const float* W = (blockIdx.z == 0) ? W0 : (blockIdx.z == 1) ? W1 : W2;
    unsigned short* T = (blockIdx.z == 0) ? T0 : (blockIdx.z == 1) ? T1 : T2;
    __shared__ __align__(16) unsigned short tile[64][65];
    int t = threadIdx.x;
    int k0 = blockIdx.y * 64, n0 = blockIdx.x * 64;
    int row = t >> 2, seg = (t & 3) * 16;
    const float* src = W + (size_t)(k0 + row) * NDIM + n0 + seg;
#pragma unroll
    for (int i = 0; i < 4; ++i) {
        float4v v = *(const float4v*)(src + i * 4);
        tile[row][seg + i*4 + 0] = bf16r(v.x);
        tile[row][seg + i*4 + 1] = bf16r(v.y);
        tile[row][seg + i*4 + 2] = bf16r(v.z);
        tile[row][seg + i*4 + 3] = bf16r(v.w);
    }
    __syncthreads();
    unsigned short* dst = T + (size_t)(n0 + row) * NDIM + k0 + seg;
#pragma unroll
    for (int i = 0; i < 4; ++i) {
        ushort4v o;
        o.x = tile[seg + i*4 + 0][row];
        o.y = tile[seg + i*4 + 1][row];
        o.z = tile[seg + i*4 + 2][row];
        o.w = tile[seg + i*4 + 3][row];
        *(ushort4v*)(dst + i*4) = o;
    }
}

// ---------- Kernel 2: projection GEMM (z=0:Q, 1:K, 2:V-transposed) ----------
#define BM 128
#define BN 128
#define BK 32

__global__ __launch_bounds__(256) void proj_gemm(
    const unsigned short* __restrict__ Xqc, const unsigned short* __restrict__ Xkc,
    const unsigned short* __restrict__ Xvc, const float* __restrict__ Xv32,
    const unsigned short* __restrict__ Tq, const unsigned short* __restrict__ Tk, const unsigned short* __restrict__ Tv,
    unsigned short* __restrict__ Oq, unsigned short* __restrict__ Ok, unsigned short* __restrict__ Ov,
    float qscale, int vasync)
{
    int z = blockIdx.z;
    const unsigned short* Xc = (z == 0) ? Xqc : (z == 1) ? Xkc : Xvc;
    const unsigned short* Wt = (z == 0) ? Tq : (z == 1) ? Tk : Tv;
    unsigned short* Out = (z == 0) ? Oq : (z == 1) ? Ok : Ov;
    float scale = (z == 0) ? qscale : 1.0f;
    bool vtrans = (z == 2);
    bool afast = (z < 2) || (vasync != 0);   // wave-uniform

    __shared__ __align__(16) unsigned short Asm[BM * BK];
    __shared__ __align__(16) unsigned short Bsm[BN * BK];

    int t = threadIdx.x;
    int wave = t >> 6, lane = t & 63, l15 = lane & 15, quad = lane >> 4;
    int m0 = blockIdx.x * BM, n0 = blockIdx.y * BN;
    int wm = (wave >> 1) * 64, wn = (wave & 1) * 64;

    float4v acc[4][4];
#pragma unroll
    for (int i = 0; i < 4; ++i)
#pragma unroll
        for (int j = 0; j < 4; ++j) acc[i][j] = (float4v){0.f, 0.f, 0.f, 0.f};

    int c0 = t, c1 = t + 256;
    const unsigned short* ga0 = Xc + (size_t)(m0 + (c0 >> 2)) * NDIM + (c0 & 3) * 8;
    const unsigned short* ga1 = Xc + (size_t)(m0 + (c1 >> 2)) * NDIM + (c1 & 3) * 8;
    const float* fa0 = Xv32 + (size_t)(m0 + (c0 >> 2)) * NDIM + (c0 & 3) * 8;
    const float* fa1 = Xv32 + (size_t)(m0 + (c1 >> 2)) * NDIM + (c1 & 3) * 8;
    const unsigned short* gb0 = Wt + (size_t)(n0 + (c0 >> 2)) * NDIM + (c0 & 3) * 8;
    const unsigned short* gb1 = Wt + (size_t)(n0 + (c1 >> 2)) * NDIM + (c1 & 3) * 8;
    unsigned short* as0 = &Asm[c0 * 8];
    unsigned short* as1 = &Asm[c1 * 8];
    unsigned short* bs0 = &Bsm[c0 * 8];
    unsigned short* bs1 = &Bsm[c1 * 8];

    for (int kt = 0; kt < NDIM; kt += BK) {
        __syncthreads();
        if (afast) {
            gl_lds16(ga0 + kt, as0);
            gl_lds16(ga1 + kt, as1);
        } else {
            float4v x0 = *(const float4v*)(fa0 + kt);
            float4v x1 = *(const float4v*)(fa0 + kt + 4);
            float4v y0 = *(const float4v*)(fa1 + kt);
            float4v y1 = *(const float4v*)(fa1 + kt + 4);
            int4v pa0, pa1;
            pa0.x = pack2(x0.x, x0.y); pa0.y = pack2(x0.z, x0.w);
            pa0.z = pack2(x1.x, x1.y); pa0.w = pack2(x1.z, x1.w);
            pa1.x = pack2(y0.x, y0.y); pa1.y = pack2(y0.z, y0.w);
            pa1.z = pack2(y1.x, y1.y); pa1.w = pack2(y1.z, y1.w);
            *(int4v*)as0 = pa0;
            *(int4v*)as1 = pa1;
        }
        gl_lds16(gb0 + kt, bs0);
        gl_lds16(gb1 + kt, bs1);
        __syncthreads();

        short8 af[4], bfr[4];
#pragma unroll
        for (int mt = 0; mt < 4; ++mt)
            af[mt] = *(const short8*)&Asm[(wm + mt * 16 + l15) * BK + quad * 8];
#pragma unroll
        for (int nt = 0; nt < 4; ++nt)
            bfr[nt] = *(const short8*)&Bsm[(wn + nt * 16 + l15) * BK + quad * 8];
#pragma unroll
        for (int mt = 0; mt < 4; ++mt)
#pragma unroll
            for (int nt = 0; nt < 4; ++nt)
                acc[mt][nt] = __builtin_amdgcn_mfma_f32_16x16x32_bf16(af[mt], bfr[nt], acc[mt][nt], 0, 0, 0);
    }

    // epilogue: C/D layout row = quad*4+reg (m), col = l15 (n)
#pragma unroll
    for (int mt = 0; mt < 4; ++mt) {
        int mbase = m0 + wm + mt * 16 + quad * 4;
        int b = mbase >> 11;
        int s = mbase & 2047;
#pragma unroll
        for (int nt = 0; nt < 4; ++nt) {
            int gn = n0 + wn + nt * 16 + l15;
            int h = gn >> 6, d = gn & 63;
            if (!vtrans) {
                size_t base = ((size_t)((b * HEADS + h) * SEQ + s)) * HDIM + d;
#pragma unroll
                for (int r = 0; r < 4; ++r)
                    Out[base + (size_t)r * HDIM] = bf16r(acc[mt][nt][r] * scale);
            } else {
                size_t base = ((size_t)((b * HEADS + h) * HDIM + d)) * SEQ + s;
                ushort4v o;
                o.x = bf16r(acc[mt][nt][0]);
                o.y = bf16r(acc[mt][nt][1]);
                o.z = bf16r(acc[mt][nt][2]);
                o.w = bf16r(acc[mt][nt][3]);
                *(ushort4v*)(Out + base) = o;
            }
        }
    }
}

// ---------- Kernel 3: flash attention ----------
// BQ=256, 4 waves x 64 q-rows. Changes vs r3 (LDS-issue was ~48% of wall,
// nothing saturated, 2 blocks/CU):
//  - V read DIRECTLY from global: KV per bh (512KB) x 8 bh/XCD = 4MB = L2-resident
//    (r3 FETCH 27.4MB confirms). Removes Vsm + V staging + 8 b128 LDS reads/chunk.
//    Both ksegs together consume full 128B L2 lines.
//  - K staged via global_load_lds into DOUBLE-BUFFERED linear Ksm[2][64*64] with
//    XOR swizzle (T2+rule#21: pre-swizzled GLOBAL source + swizzled ds_read;
//    LDS cell (row,x) holds d-block x^(row&7); read of block w fetches w).
//    One barrier per chunk (T3-minimum); staging in flight across whole chunk.
//  - LDS 52KB total (<=64KB rule from r4: 73.7KB dropped residency to 1 block/CU).
// Key permutation trick unchanged: QK MFMA nt reads K-row l15*4+nt, lane
// (quad,l15) holds scores for keys {4*l15..4*l15+3}; PV sums keys in true order,
// so the permutation cancels.
#define BQ  256
#define BKC 64

__global__ __launch_bounds__(256) void attn_kernel(
    const unsigned short* __restrict__ Q,    // [B][H][S][64] bf16, pre-scaled by 0.125*log2(e)
    const unsigned short* __restrict__ K,    // [B][H][S][64] bf16
    const unsigned short* __restrict__ Vt,   // [B][H][64][S] bf16
    float* __restrict__ Out)                 // [B][S][1024] fp32
{
    __shared__ __align__(16) unsigned short Ksm[2][BKC * HDIM];  // 2 x 8KB, swizzled linear
    __shared__ __align__(16) unsigned short Psm[4][64][72];

    int t = threadIdx.x;
    int wave = t >> 6, lane = t & 63, l15 = lane & 15, quad = lane >> 4;
    int L = blockIdx.x;
    int bh = L & 63;
    int b = bh >> 4, h = bh & 15;
    int q0 = (L >> 6) * BQ;

    const unsigned short* Qbh = Q + (size_t)bh * SEQ * HDIM;
    const unsigned short* Kbh = K + (size_t)bh * SEQ * HDIM;
    const unsigned short* Vbh = Vt + (size_t)bh * HDIM * SEQ;

    short8 qf[4][2];
#pragma unroll
    for (int mt = 0; mt < 4; ++mt) {
        int qr = q0 + wave * 64 + mt * 16 + l15;
        qf[mt][0] = *(const short8*)(Qbh + (size_t)qr * HDIM + quad * 8);
        qf[mt][1] = *(const short8*)(Qbh + (size_t)qr * HDIM + 32 + quad * 8);
    }

    float lsum[4][4];
    float4v acc_o[4][4];
#pragma unroll
    for (int mt = 0; mt < 4; ++mt) {
#pragma unroll
        for (int r = 0; r < 4; ++r) lsum[mt][r] = 0.f;
#pragma unroll
        for (int dtt = 0; dtt < 4; ++dtt) acc_o[mt][dtt] = (float4v){0.f, 0.f, 0.f, 0.f};
    }

    // K staging: thread t fills LDS 16B-blocks t and t+256.
    // LDS block t -> (row = t>>3, c16 = t&7); source d-block = c16 ^ (row&7).
    // Second block: row+32 -> same swizzle (32&7==0).
    int srow = t >> 3;                        // 0..31
    int sc16 = (t & 7) ^ (srow & 7);          // pre-swizzled global d-block
    const unsigned short* ksrc = Kbh + (size_t)srow * HDIM + sc16 * 8;

    // prologue: stage chunk 0 into buf 0 (barrier's implicit vmcnt(0) covers DMA)
    gl_lds16(ksrc, &Ksm[0][t * 8]);
    gl_lds16(ksrc + 32 * HDIM, &Ksm[0][(t + 256) * 8]);
    __syncthreads();

    int cur = 0;
    for (int kc = 0; kc < SEQ; kc += BKC) {
        bool more = (kc + BKC < SEQ);
        if (more) {   // async-stage next K chunk; in flight across this chunk's compute
            const unsigned short* ks = ksrc + (size_t)(kc + BKC) * HDIM;
            gl_lds16(ks, &Ksm[cur ^ 1][t * 8]);
            gl_lds16(ks + 32 * HDIM, &Ksm[cur ^ 1][(t + 256) * 8]);
        }

        // vf kseg0: direct global (L2); latency covered by QK+softmax below
        short8 vf0[4];
#pragma unroll
        for (int dtt = 0; dtt < 4; ++dtt)
            vf0[dtt] = *(const short8*)(Vbh + (size_t)(dtt * 16 + l15) * SEQ + kc + quad * 8);

        // K fragments from swizzled LDS, reused by all 4 mt
        const unsigned short* K0 = &Ksm[cur][0];
        short8 kf[4][2];
#pragma unroll
        for (int nt = 0; nt < 4; ++nt) {
            int row = l15 * 4 + nt;
            int sw = row & 7;
            kf[nt][0] = *(const short8*)&K0[row * 64 + ((quad ^ sw) * 8)];
            kf[nt][1] = *(const short8*)&K0[row * 64 + (((quad + 4) ^ sw) * 8)];
        }

        // per-mt: S = Q K^T then softmax+P-write (keeps sc live range at 16 VGPR)
#pragma unroll
        for (int mt = 0; mt < 4; ++mt) {
            float4v sc[4];
#pragma unroll
            for (int nt = 0; nt < 4; ++nt) sc[nt] = (float4v){0.f, 0.f, 0.f, 0.f};
            __builtin_amdgcn_s_setprio(1);
#pragma unroll
            for (int nt = 0; nt < 4; ++nt) {
                sc[nt] = __builtin_amdgcn_mfma_f32_16x16x32_bf16(qf[mt][0], kf[nt][0], sc[nt], 0, 0, 0);
                sc[nt] = __builtin_amdgcn_mfma_f32_16x16x32_bf16(qf[mt][1], kf[nt][1], sc[nt], 0, 0, 0);
            }
            __builtin_amdgcn_s_setprio(0);

            // fixed-max softmax: p = exp2(s); lane's 4 nt-values are keys 4*l15..+3.
#pragma unroll
            for (int r = 0; r < 4; ++r) {
                float p0 = __builtin_amdgcn_exp2f(sc[0][r]);
                float p1 = __builtin_amdgcn_exp2f(sc[1][r]);
                float p2 = __builtin_amdgcn_exp2f(sc[2][r]);
                float p3 = __builtin_amdgcn_exp2f(sc[3][r]);
                lsum[mt][r] += (p0 + p1) + (p2 + p3);
                int row = mt * 16 + quad * 4 + r;
                int2v pw;
                pw.x = (int)cvt_pk_bf16(p0, p1);
                pw.y = (int)cvt_pk_bf16(p2, p3);
                *(int2v*)&Psm[wave][row][l15 * 4] = pw;
            }
        }

        // vf kseg1: issue before PV kseg0 so its L2 latency hides under those MFMAs
        short8 vf1[4];
#pragma unroll
        for (int dtt = 0; dtt < 4; ++dtt)
            vf1[dtt] = *(const short8*)(Vbh + (size_t)(dtt * 16 + l15) * SEQ + kc + 32 + quad * 8);

        // PV: O += P V  (Psm wave-private; lgkmcnt covers the RAW)
        __builtin_amdgcn_s_setprio(1);
        {
            short8 pf[4];
#pragma unroll
            for (int mt = 0; mt < 4; ++mt)
                pf[mt] = *(const short8*)&Psm[wave][mt * 16 + l15][quad * 8];
#pragma unroll
            for (int mt = 0; mt < 4; ++mt)
#pragma unroll
                for (int dtt = 0; dtt < 4; ++dtt)
                    acc_o[mt][dtt] = __builtin_amdgcn_mfma_f32_16x16x32_bf16(pf[mt], vf0[dtt], acc_o[mt][dtt], 0, 0, 0);
        }
        {
            short8 pf[4];
#pragma unroll
            for (int mt = 0; mt < 4; ++mt)
                pf[mt] = *(const short8*)&Psm[wave][mt * 16 + l15][32 + quad * 8];
#pragma unroll
            for (int mt = 0; mt < 4; ++mt)
#pragma unroll
                for (int dtt = 0; dtt < 4; ++dtt)
                    acc_o[mt][dtt] = __builtin_amdgcn_mfma_f32_16x16x32_bf16(pf[mt], vf1[dtt], acc_o[mt][dtt], 0, 0, 0);
        }
        __builtin_amdgcn_s_setprio(0);

        // single barrier per chunk: separates this chunk's Ksm[cur] reads from
        // next chunk's DMA into it; implicit vmcnt(0) drains the staging DMA.
        if (more) {
            __syncthreads();
            cur ^= 1;
        }
    }

#pragma unroll
    for (int mt = 0; mt < 4; ++mt)
#pragma unroll
        for (int r = 0; r < 4; ++r) {
            float l = lsum[mt][r];
            l += __shfl_xor(l, 1);
            l += __shfl_xor(l, 2);
            l += __shfl_xor(l, 4);
            l += __shfl_xor(l, 8);
            float inv = 1.0f / l;
            int qrow = q0 + wave * 64 + mt * 16 + quad * 4 + r;
            size_t base = ((size_t)(b * SEQ + qrow)) * NDIM + h * HDIM;
#pragma unroll
            for (int dtt = 0; dtt < 4; ++dtt)
                Out[base + dtt * 16 + l15] = acc_o[mt][dtt][r] * inv;
        }
}

extern "C" void kernel_launch(void* const* d_in, const int* in_sizes, int n_in,
                              void* d_out, int out_size, void* d_ws, size_t ws_size,
                              hipStream_t stream)
{
    const float* q_in = (const float*)d_in[0];
    const float* k_in = (const float*)d_in[1];
    const float* v_in = (const float*)d_in[2];
    const float* WQ = (const float*)d_in[3];
    const float* WK = (const float*)d_in[4];
    const float* WV = (const float*)d_in[5];
    float* out = (float*)d_out;

    unsigned short* ws = (unsigned short*)d_ws;
    size_t wsz = (size_t)NDIM * NDIM;
    size_t psz = (size_t)MTOT * NDIM;
    unsigned short* Tq = ws;
    unsigned short* Tk = Tq + wsz;
    unsigned short* Tv = Tk + wsz;
    unsigned short* Qp = Tv + wsz;
    unsigned short* Kp = Qp + psz;
    unsigned short* Vp = Kp + psz;
    unsigned short* Xvc = Vp + psz;

    unsigned short* Xqc = (unsigned short*)d_out;
    unsigned short* Xkc = Xqc + psz;

    size_t need = (3 * wsz + 4 * psz) * sizeof(unsigned short);
    int vasync = (ws_size >= need) ? 1 : 0;

    cast_x<<<dim3(MTOT * NDIM / (256 * 8), 1, vasync ? 3 : 2), 256, 0, stream>>>(
        q_in, k_in, v_in, Xqc, Xkc, Xvc);
    cast_transpose_w<<<dim3(16, 16, 3), 256, 0, stream>>>(WQ, WK, WV, Tq, Tk, Tv);
    proj_gemm<<<dim3(MTOT / BM, NDIM / BN, 3), 256, 0, stream>>>(
        Xqc, Xkc, Xvc, v_in, Tq, Tk, Tv, Qp, Kp, Vp, 0.125f * 1.44269504088896f, vasync);
    attn_kernel<<<dim3(SEQ / BQ * BATCH * HEADS), 256, 0, stream>>>(Qp, Kp, Vp, out);
}

// Round 6
// 345.894 us; speedup vs baseline: 1.0364x; 1.0364x over previous
//
#include <hip/hip_runtime.h>
#include <stdint.h>

#define HEADS 16
#define HDIM  64
#define NDIM  1024
#define BATCH 4
#define SEQ   2048
#define MTOT  (BATCH * SEQ)   // 8192

typedef __attribute__((ext_vector_type(8))) short short8;
typedef __attribute__((ext_vector_type(4))) float float4v;
typedef __attribute__((ext_vector_type(4))) int int4v;
typedef __attribute__((ext_vector_type(2))) int int2v;
typedef __attribute__((ext_vector_type(4))) unsigned short ushort4v;

static __device__ __forceinline__ unsigned int fbits(float f) {
    union { float f; unsigned int u; } v; v.f = f; return v.u;
}
static __device__ __forceinline__ unsigned short bf16r(float f) {
    return (unsigned short)((fbits(f) + 0x8000u) >> 16);
}
static __device__ __forceinline__ unsigned int pack2(float lo, float hi) {
    return ((fbits(hi) + 0x8000u) & 0xffff0000u) | ((fbits(lo) + 0x8000u) >> 16);
}
// two f32 -> packed bf16x2 in one VALU op (T12 primitive).
static __device__ __forceinline__ unsigned int cvt_pk_bf16(float lo, float hi) {
    unsigned int r;
    asm("v_cvt_pk_bf16_f32 %0, %1, %2" : "=v"(r) : "v"(lo), "v"(hi));
    return r;
}

// async 16B global->LDS (m97 pattern)
static __device__ __forceinline__ void gl_lds16(const unsigned short* g, unsigned short* l) {
    __builtin_amdgcn_global_load_lds(
        (const __attribute__((address_space(1))) unsigned int*)(uintptr_t)g,
        (__attribute__((address_space(3))) unsigned int*)(uintptr_t)l,
        16, 0, 0);
}

// ---------- Kernel 1: Wt[n][k] = bf16(W[k][n]) ----------
__global__ __launch_bounds__(256) void cast_transpose_w(
    const float* __restrict__ W0, const float* __restrict__ W1, const float* __restrict__ W2,
    unsigned short* __restrict__ T0, unsigned short* __restrict__ T1, unsigned short* __restrict__ T2)
{
    const float* W = (blockIdx.z == 0) ? W0 : (blockIdx.z == 1) ? W1 : W2;
    unsigned short* T = (blockIdx.z == 0) ? T0 : (blockIdx.z == 1) ? T1 : T2;
    __shared__ __align__(16) unsigned short tile[64][65];
    int t = threadIdx.x;
    int k0 = blockIdx.y * 64, n0 = blockIdx.x * 64;
    int row = t >> 2, seg = (t & 3) * 16;
    const float* src = W + (size_t)(k0 + row) * NDIM + n0 + seg;
#pragma unroll
    for (int i = 0; i < 4; ++i) {
        float4v v = *(const float4v*)(src + i * 4);
        tile[row][seg + i*4 + 0] = bf16r(v.x);
        tile[row][seg + i*4 + 1] = bf16r(v.y);
        tile[row][seg + i*4 + 2] = bf16r(v.z);
        tile[row][seg + i*4 + 3] = bf16r(v.w);
    }
    __syncthreads();
    unsigned short* dst = T + (size_t)(n0 + row) * NDIM + k0 + seg;
#pragma unroll
    for (int i = 0; i < 4; ++i) {
        ushort4v o;
        o.x = tile[seg + i*4 + 0][row];
        o.y = tile[seg + i*4 + 1][row];
        o.z = tile[seg + i*4 + 2][row];
        o.w = tile[seg + i*4 + 3][row];
        *(ushort4v*)(dst + i*4) = o;
    }
}

// ---------- Kernel 2: projection GEMM (z=0:Q, 1:K, 2:V-transposed) ----------
// A (activations) read directly as FP32 and packed to bf16 during LDS staging
// (the previously-proven vasync=0 path, now the only path) -> cast_x kernel
// deleted, saving its ~150MB HBM round-trip. B staged bf16 via global_load_lds.
// grid (64 m-blocks, 8 n-blocks, 3): XCD = linear%8 = m%8 -> each XCD's 8
// A-panels stay L2-resident across the whole n-sweep.
#define BM 128
#define BN 128
#define BK 32

__global__ __launch_bounds__(256) void proj_gemm(
    const float* __restrict__ Xq32, const float* __restrict__ Xk32, const float* __restrict__ Xv32,
    const unsigned short* __restrict__ Tq, const unsigned short* __restrict__ Tk, const unsigned short* __restrict__ Tv,
    unsigned short* __restrict__ Oq, unsigned short* __restrict__ Ok, unsigned short* __restrict__ Ov,
    float qscale)
{
    int z = blockIdx.z;
    const float* X32 = (z == 0) ? Xq32 : (z == 1) ? Xk32 : Xv32;
    const unsigned short* Wt = (z == 0) ? Tq : (z == 1) ? Tk : Tv;
    unsigned short* Out = (z == 0) ? Oq : (z == 1) ? Ok : Ov;
    float scale = (z == 0) ? qscale : 1.0f;
    bool vtrans = (z == 2);

    __shared__ __align__(16) unsigned short Asm[BM * BK];
    __shared__ __align__(16) unsigned short Bsm[BN * BK];

    int t = threadIdx.x;
    int wave = t >> 6, lane = t & 63, l15 = lane & 15, quad = lane >> 4;
    int m0 = blockIdx.x * BM, n0 = blockIdx.y * BN;
    int wm = (wave >> 1) * 64, wn = (wave & 1) * 64;

    float4v acc[4][4];
#pragma unroll
    for (int i = 0; i < 4; ++i)
#pragma unroll
        for (int j = 0; j < 4; ++j) acc[i][j] = (float4v){0.f, 0.f, 0.f, 0.f};

    int c0 = t, c1 = t + 256;
    const float* fa0 = X32 + (size_t)(m0 + (c0 >> 2)) * NDIM + (c0 & 3) * 8;
    const float* fa1 = X32 + (size_t)(m0 + (c1 >> 2)) * NDIM + (c1 & 3) * 8;
    const unsigned short* gb0 = Wt + (size_t)(n0 + (c0 >> 2)) * NDIM + (c0 & 3) * 8;
    const unsigned short* gb1 = Wt + (size_t)(n0 + (c1 >> 2)) * NDIM + (c1 & 3) * 8;
    unsigned short* as0 = &Asm[c0 * 8];
    unsigned short* as1 = &Asm[c1 * 8];
    unsigned short* bs0 = &Bsm[c0 * 8];
    unsigned short* bs1 = &Bsm[c1 * 8];

    for (int kt = 0; kt < NDIM; kt += BK) {
        __syncthreads();
        {
            float4v x0 = *(const float4v*)(fa0 + kt);
            float4v x1 = *(const float4v*)(fa0 + kt + 4);
            float4v y0 = *(const float4v*)(fa1 + kt);
            float4v y1 = *(const float4v*)(fa1 + kt + 4);
            int4v pa0, pa1;
            pa0.x = pack2(x0.x, x0.y); pa0.y = pack2(x0.z, x0.w);
            pa0.z = pack2(x1.x, x1.y); pa0.w = pack2(x1.z, x1.w);
            pa1.x = pack2(y0.x, y0.y); pa1.y = pack2(y0.z, y0.w);
            pa1.z = pack2(y1.x, y1.y); pa1.w = pack2(y1.z, y1.w);
            *(int4v*)as0 = pa0;
            *(int4v*)as1 = pa1;
        }
        gl_lds16(gb0 + kt, bs0);
        gl_lds16(gb1 + kt, bs1);
        __syncthreads();

        short8 af[4], bfr[4];
#pragma unroll
        for (int mt = 0; mt < 4; ++mt)
            af[mt] = *(const short8*)&Asm[(wm + mt * 16 + l15) * BK + quad * 8];
#pragma unroll
        for (int nt = 0; nt < 4; ++nt)
            bfr[nt] = *(const short8*)&Bsm[(wn + nt * 16 + l15) * BK + quad * 8];
#pragma unroll
        for (int mt = 0; mt < 4; ++mt)
#pragma unroll
            for (int nt = 0; nt < 4; ++nt)
                acc[mt][nt] = __builtin_amdgcn_mfma_f32_16x16x32_bf16(af[mt], bfr[nt], acc[mt][nt], 0, 0, 0);
    }

    // epilogue: C/D layout row = quad*4+reg (m), col = l15 (n)
#pragma unroll
    for (int mt = 0; mt < 4; ++mt) {
        int mbase = m0 + wm + mt * 16 + quad * 4;
        int b = mbase >> 11;
        int s = mbase & 2047;
#pragma unroll
        for (int nt = 0; nt < 4; ++nt) {
            int gn = n0 + wn + nt * 16 + l15;
            int h = gn >> 6, d = gn & 63;
            if (!vtrans) {
                size_t base = ((size_t)((b * HEADS + h) * SEQ + s)) * HDIM + d;
#pragma unroll
                for (int r = 0; r < 4; ++r)
                    Out[base + (size_t)r * HDIM] = bf16r(acc[mt][nt][r] * scale);
            } else {
                size_t base = ((size_t)((b * HEADS + h) * HDIM + d)) * SEQ + s;
                ushort4v o;
                o.x = bf16r(acc[mt][nt][0]);
                o.y = bf16r(acc[mt][nt][1]);
                o.z = bf16r(acc[mt][nt][2]);
                o.w = bf16r(acc[mt][nt][3]);
                *(ushort4v*)(Out + base) = o;
            }
        }
    }
}

// ---------- Kernel 3: flash attention (exact r3 configuration, best measured) ----------
// BQ=256: each of 4 waves owns 64 q-rows (mt=0..3). K/V fragments reused across
// 4 mt. Single-buffered K/V (55.3KB LDS -> 2 blocks/CU), register prefetch of
// next chunk, 2 barriers/chunk. Pad-72 rows: row stride = 36 banks -> fragment
// reads conflict at the free 2-way level (r5 lesson: XOR swizzle with row&7
// barely varying made it WORSE; do not re-enter without new counter evidence).
// Key permutation trick: QK MFMA nt reads K-row l15*4+nt, lane (quad,l15) holds
// scores for keys {4*l15..4*l15+3}; PV sums keys in true order from Vsm, so the
// permutation cancels.
#define BQ  256
#define BKC 64

__global__ __launch_bounds__(256) void attn_kernel(
    const unsigned short* __restrict__ Q,    // [B][H][S][64] bf16, pre-scaled by 0.125*log2(e)
    const unsigned short* __restrict__ K,    // [B][H][S][64] bf16
    const unsigned short* __restrict__ Vt,   // [B][H][64][S] bf16
    float* __restrict__ Out)                 // [B][S][1024] fp32
{
    __shared__ __align__(16) unsigned short Ksm[BKC][72];
    __shared__ __align__(16) unsigned short Vsm[HDIM][72];
    __shared__ __align__(16) unsigned short Psm[4][64][72];

    int t = threadIdx.x;
    int wave = t >> 6, lane = t & 63, l15 = lane & 15, quad = lane >> 4;
    int L = blockIdx.x;
    int bh = L & 63;
    int b = bh >> 4, h = bh & 15;
    int q0 = (L >> 6) * BQ;

    const unsigned short* Qbh = Q + (size_t)bh * SEQ * HDIM;
    const unsigned short* Kbh = K + (size_t)bh * SEQ * HDIM;
    const unsigned short* Vbh = Vt + (size_t)bh * HDIM * SEQ;

    short8 qf[4][2];
#pragma unroll
    for (int mt = 0; mt < 4; ++mt) {
        int qr = q0 + wave * 64 + mt * 16 + l15;
        qf[mt][0] = *(const short8*)(Qbh + (size_t)qr * HDIM + quad * 8);
        qf[mt][1] = *(const short8*)(Qbh + (size_t)qr * HDIM + 32 + quad * 8);
    }

    float lsum[4][4];
    float4v acc_o[4][4];
#pragma unroll
    for (int mt = 0; mt < 4; ++mt) {
#pragma unroll
        for (int r = 0; r < 4; ++r) lsum[mt][r] = 0.f;
#pragma unroll
        for (int dtt = 0; dtt < 4; ++dtt) acc_o[mt][dtt] = (float4v){0.f, 0.f, 0.f, 0.f};
    }

    int srow = t >> 2;            // 0..63
    int sseg = (t & 3) * 16;
    const unsigned short* kptr = Kbh + (size_t)srow * HDIM + sseg;
    const unsigned short* vptr = Vbh + (size_t)srow * SEQ + sseg;

    // prefetch chunk 0 into registers
    short8 kv0 = *(const short8*)(kptr);
    short8 kv1 = *(const short8*)(kptr + 8);
    short8 kv2 = *(const short8*)(vptr);
    short8 kv3 = *(const short8*)(vptr + 8);

    for (int kc = 0; kc < SEQ; kc += BKC) {
        __syncthreads();
        *(short8*)&Ksm[srow][sseg]     = kv0;
        *(short8*)&Ksm[srow][sseg + 8] = kv1;
        *(short8*)&Vsm[srow][sseg]     = kv2;
        *(short8*)&Vsm[srow][sseg + 8] = kv3;
        __syncthreads();

        int kn = kc + BKC;
        if (kn < SEQ) {   // prefetch next chunk; latency hidden under this chunk's compute
            kv0 = *(const short8*)(kptr + (size_t)kn * HDIM);
            kv1 = *(const short8*)(kptr + (size_t)kn * HDIM + 8);
            kv2 = *(const short8*)(vptr + kn);
            kv3 = *(const short8*)(vptr + kn + 8);
        }

        // K fragments hoisted once per chunk, reused by all 4 mt
        short8 kf[4][2];
#pragma unroll
        for (int nt = 0; nt < 4; ++nt) {
            kf[nt][0] = *(const short8*)&Ksm[l15 * 4 + nt][quad * 8];
            kf[nt][1] = *(const short8*)&Ksm[l15 * 4 + nt][32 + quad * 8];
        }

        // per-mt: S = Q K^T then softmax+P-write (keeps sc live range at 16 VGPR)
#pragma unroll
        for (int mt = 0; mt < 4; ++mt) {
            float4v sc[4];
#pragma unroll
            for (int nt = 0; nt < 4; ++nt) sc[nt] = (float4v){0.f, 0.f, 0.f, 0.f};
            __builtin_amdgcn_s_setprio(1);
#pragma unroll
            for (int nt = 0; nt < 4; ++nt) {
                sc[nt] = __builtin_amdgcn_mfma_f32_16x16x32_bf16(qf[mt][0], kf[nt][0], sc[nt], 0, 0, 0);
                sc[nt] = __builtin_amdgcn_mfma_f32_16x16x32_bf16(qf[mt][1], kf[nt][1], sc[nt], 0, 0, 0);
            }
            __builtin_amdgcn_s_setprio(0);

            // fixed-max softmax: p = exp2(s); lane's 4 nt-values are keys 4*l15..+3.
#pragma unroll
            for (int r = 0; r < 4; ++r) {
                float p0 = __builtin_amdgcn_exp2f(sc[0][r]);
                float p1 = __builtin_amdgcn_exp2f(sc[1][r]);
                float p2 = __builtin_amdgcn_exp2f(sc[2][r]);
                float p3 = __builtin_amdgcn_exp2f(sc[3][r]);
                lsum[mt][r] += (p0 + p1) + (p2 + p3);
                int row = mt * 16 + quad * 4 + r;
                int2v pw;
                pw.x = (int)cvt_pk_bf16(p0, p1);
                pw.y = (int)cvt_pk_bf16(p2, p3);
                *(int2v*)&Psm[wave][row][l15 * 4] = pw;
            }
        }

        // PV: O += P V  (Psm wave-private; lgkmcnt covers the RAW)
        __builtin_amdgcn_s_setprio(1);
#pragma unroll
        for (int kseg = 0; kseg < 2; ++kseg) {
            short8 pf[4], vf[4];
#pragma unroll
            for (int mt = 0; mt < 4; ++mt)
                pf[mt] = *(const short8*)&Psm[wave][mt * 16 + l15][kseg * 32 + quad * 8];
#pragma unroll
            for (int dtt = 0; dtt < 4; ++dtt)
                vf[dtt] = *(const short8*)&Vsm[dtt * 16 + l15][kseg * 32 + quad * 8];
#pragma unroll
            for (int mt = 0; mt < 4; ++mt)
#pragma unroll
                for (int dtt = 0; dtt < 4; ++dtt)
                    acc_o[mt][dtt] = __builtin_amdgcn_mfma_f32_16x16x32_bf16(pf[mt], vf[dtt], acc_o[mt][dtt], 0, 0, 0);
        }
        __builtin_amdgcn_s_setprio(0);
    }

#pragma unroll
    for (int mt = 0; mt < 4; ++mt)
#pragma unroll
        for (int r = 0; r < 4; ++r) {
            float l = lsum[mt][r];
            l += __shfl_xor(l, 1);
            l += __shfl_xor(l, 2);
            l += __shfl_xor(l, 4);
            l += __shfl_xor(l, 8);
            float inv = 1.0f / l;
            int qrow = q0 + wave * 64 + mt * 16 + quad * 4 + r;
            size_t base = ((size_t)(b * SEQ + qrow)) * NDIM + h * HDIM;
#pragma unroll
            for (int dtt = 0; dtt < 4; ++dtt)
                Out[base + dtt * 16 + l15] = acc_o[mt][dtt][r] * inv;
        }
}

extern "C" void kernel_launch(void* const* d_in, const int* in_sizes, int n_in,
                              void* d_out, int out_size, void* d_ws, size_t ws_size,
                              hipStream_t stream)
{
    const float* q_in = (const float*)d_in[0];
    const float* k_in = (const float*)d_in[1];
    const float* v_in = (const float*)d_in[2];
    const float* WQ = (const float*)d_in[3];
    const float* WK = (const float*)d_in[4];
    const float* WV = (const float*)d_in[5];
    float* out = (float*)d_out;

    unsigned short* ws = (unsigned short*)d_ws;
    size_t wsz = (size_t)NDIM * NDIM;
    size_t psz = (size_t)MTOT * NDIM;
    unsigned short* Tq = ws;
    unsigned short* Tk = Tq + wsz;
    unsigned short* Tv = Tk + wsz;
    unsigned short* Qp = Tv + wsz;
    unsigned short* Kp = Qp + psz;
    unsigned short* Vp = Kp + psz;

    cast_transpose_w<<<dim3(16, 16, 3), 256, 0, stream>>>(WQ, WK, WV, Tq, Tk, Tv);
    proj_gemm<<<dim3(MTOT / BM, NDIM / BN, 3), 256, 0, stream>>>(
        q_in, k_in, v_in, Tq, Tk, Tv, Qp, Kp, Vp, 0.125f * 1.44269504088896f);
    attn_kernel<<<dim3(SEQ / BQ * BATCH * HEADS), 256, 0, stream>>>(Qp, Kp, Vp, out);
}

// Round 7
// 287.733 us; speedup vs baseline: 1.2459x; 1.2021x over previous
//
#include <hip/hip_runtime.h>
#include <stdint.h>

#define HEADS 16
#define HDIM  64
#define NDIM  1024
#define BATCH 4
#define SEQ   2048
#define MTOT  (BATCH * SEQ)   // 8192

typedef __attribute__((ext_vector_type(8))) short short8;
typedef __attribute__((ext_vector_type(4))) float float4v;
typedef __attribute__((ext_vector_type(4))) int int4v;
typedef __attribute__((ext_vector_type(2))) int int2v;
typedef __attribute__((ext_vector_type(4))) unsigned short ushort4v;

static __device__ __forceinline__ unsigned int fbits(float f) {
    union { float f; unsigned int u; } v; v.f = f; return v.u;
}
static __device__ __forceinline__ unsigned short bf16r(float f) {
    return (unsigned short)((fbits(f) + 0x8000u) >> 16);
}
static __device__ __forceinline__ unsigned int pack2(float lo, float hi) {
    return ((fbits(hi) + 0x8000u) & 0xffff0000u) | ((fbits(lo) + 0x8000u) >> 16);
}
// two f32 -> packed bf16x2 in one VALU op (T12 primitive).
static __device__ __forceinline__ unsigned int cvt_pk_bf16(float lo, float hi) {
    unsigned int r;
    asm("v_cvt_pk_bf16_f32 %0, %1, %2" : "=v"(r) : "v"(lo), "v"(hi));
    return r;
}

// async 16B global->LDS (m97 pattern)
static __device__ __forceinline__ void gl_lds16(const unsigned short* g, unsigned short* l) {
    __builtin_amdgcn_global_load_lds(
        (const __attribute__((address_space(1))) unsigned int*)(uintptr_t)g,
        (__attribute__((address_space(3))) unsigned int*)(uintptr_t)l,
        16, 0, 0);
}

// ---------- Kernel 0: cast X fp32 -> bf16 (contiguous) ----------
// Restored (r6 lesson: fusing the pack into proj's staging replaced async DMA
// with serial reg-round-trip staging -> proj 95->157us. Never again.)
__global__ __launch_bounds__(256) void cast_x(
    const float* __restrict__ X0, const float* __restrict__ X1, const float* __restrict__ X2,
    unsigned short* __restrict__ Y0, unsigned short* __restrict__ Y1, unsigned short* __restrict__ Y2)
{
    int z = blockIdx.z;
    const float* X = (z == 0) ? X0 : (z == 1) ? X1 : X2;
    unsigned short* Y = (z == 0) ? Y0 : (z == 1) ? Y1 : Y2;
    size_t i = ((size_t)blockIdx.x * 256 + threadIdx.x) * 8;
    float4v a = *(const float4v*)(X + i);
    float4v b = *(const float4v*)(X + i + 4);
    int4v p;
    p.x = pack2(a.x, a.y); p.y = pack2(a.z, a.w);
    p.z = pack2(b.x, b.y); p.w = pack2(b.z, b.w);
    *(int4v*)(Y + i) = p;
}

// ---------- Kernel 1: Wt[n][k] = bf16(W[k][n]) ----------
__global__ __launch_bounds__(256) void cast_transpose_w(
    const float* __restrict__ W0, const float* __restrict__ W1, const float* __restrict__ W2,
    unsigned short* __restrict__ T0, unsigned short* __restrict__ T1, unsigned short* __restrict__ T2)
{
    const float* W = (blockIdx.z == 0) ? W0 : (blockIdx.z == 1) ? W1 : W2;
    unsigned short* T = (blockIdx.z == 0) ? T0 : (blockIdx.z == 1) ? T1 : T2;
    __shared__ __align__(16) unsigned short tile[64][65];
    int t = threadIdx.x;
    int k0 = blockIdx.y * 64, n0 = blockIdx.x * 64;
    int row = t >> 2, seg = (t & 3) * 16;
    const float* src = W + (size_t)(k0 + row) * NDIM + n0 + seg;
#pragma unroll
    for (int i = 0; i < 4; ++i) {
        float4v v = *(const float4v*)(src + i * 4);
        tile[row][seg + i*4 + 0] = bf16r(v.x);
        tile[row][seg + i*4 + 1] = bf16r(v.y);
        tile[row][seg + i*4 + 2] = bf16r(v.z);
        tile[row][seg + i*4 + 3] = bf16r(v.w);
    }
    __syncthreads();
    unsigned short* dst = T + (size_t)(n0 + row) * NDIM + k0 + seg;
#pragma unroll
    for (int i = 0; i < 4; ++i) {
        ushort4v o;
        o.x = tile[seg + i*4 + 0][row];
        o.y = tile[seg + i*4 + 1][row];
        o.z = tile[seg + i*4 + 2][row];
        o.w = tile[seg + i*4 + 3][row];
        *(ushort4v*)(dst + i*4) = o;
    }
}

// ---------- Kernel 2: projection GEMM (z=0:Q, 1:K, 2:V-transposed) ----------
// bf16 A+B via global_load_lds (r2-proven). BK=64: halves barrier count (m233:
// 2-phase critical path is stage+vmcnt+barrier). At BK=64 the row stride is
// 128B = full bank cycle, so fragment reads REQUIRE the T2 XOR swizzle:
// linear DMA dest + pre-swizzled global source + swizzled ds_read (rule #21).
// LDS cell (row, blk) holds global 16B-block blk^(row&7); read of block w at
// row fetches (w^(row&7))^(row&7) = w. Here row&7 = l15&7 spans all 8 values
// across the 16 conflicting lanes (unlike r5's attn case) -> 8 lanes per
// 4-bank group = capacity minimum, conflict-free.
#define BM 128
#define BN 128
#define BK 64

__global__ __launch_bounds__(256) void proj_gemm(
    const unsigned short* __restrict__ Xqc, const unsigned short* __restrict__ Xkc,
    const unsigned short* __restrict__ Xvc,
    const unsigned short* __restrict__ Tq, const unsigned short* __restrict__ Tk, const unsigned short* __restrict__ Tv,
    unsigned short* __restrict__ Oq, unsigned short* __restrict__ Ok, unsigned short* __restrict__ Ov,
    float qscale)
{
    int z = blockIdx.z;
    const unsigned short* Xc = (z == 0) ? Xqc : (z == 1) ? Xkc : Xvc;
    const unsigned short* Wt = (z == 0) ? Tq : (z == 1) ? Tk : Tv;
    unsigned short* Out = (z == 0) ? Oq : (z == 1) ? Ok : Ov;
    float scale = (z == 0) ? qscale : 1.0f;
    bool vtrans = (z == 2);

    __shared__ __align__(16) unsigned short Asm[BM * BK];   // 16KB, swizzled blocks
    __shared__ __align__(16) unsigned short Bsm[BN * BK];   // 16KB

    int t = threadIdx.x;
    int wave = t >> 6, lane = t & 63, l15 = lane & 15, quad = lane >> 4;
    int m0 = blockIdx.x * BM, n0 = blockIdx.y * BN;
    int wm = (wave >> 1) * 64, wn = (wave & 1) * 64;

    float4v acc[4][4];
#pragma unroll
    for (int i = 0; i < 4; ++i)
#pragma unroll
        for (int j = 0; j < 4; ++j) acc[i][j] = (float4v){0.f, 0.f, 0.f, 0.f};

    // staging: thread t fills LDS 16B-blocks t, t+256, t+512, t+768.
    // LDS block c -> (row = c>>3, blk = c&7); global source block = blk^(row&7).
    const unsigned short* gaP[4];
    const unsigned short* gbP[4];
    unsigned short* asP[4];
    unsigned short* bsP[4];
#pragma unroll
    for (int i = 0; i < 4; ++i) {
        int c = t + i * 256;
        int row = c >> 3;
        int blk = (c & 7) ^ (row & 7);
        gaP[i] = Xc + (size_t)(m0 + row) * NDIM + blk * 8;
        gbP[i] = Wt + (size_t)(n0 + row) * NDIM + blk * 8;
        asP[i] = &Asm[c * 8];
        bsP[i] = &Bsm[c * 8];
    }

    for (int kt = 0; kt < NDIM; kt += BK) {
        __syncthreads();
#pragma unroll
        for (int i = 0; i < 4; ++i) {
            gl_lds16(gaP[i] + kt, asP[i]);
            gl_lds16(gbP[i] + kt, bsP[i]);
        }
        __syncthreads();

#pragma unroll
        for (int ksub = 0; ksub < 2; ++ksub) {
            short8 af[4], bfr[4];
#pragma unroll
            for (int mt = 0; mt < 4; ++mt) {
                int row = wm + mt * 16 + l15;
                af[mt] = *(const short8*)&Asm[row * BK + (((ksub * 4 + quad) ^ (row & 7)) * 8)];
            }
#pragma unroll
            for (int nt = 0; nt < 4; ++nt) {
                int row = wn + nt * 16 + l15;
                bfr[nt] = *(const short8*)&Bsm[row * BK + (((ksub * 4 + quad) ^ (row & 7)) * 8)];
            }
#pragma unroll
            for (int mt = 0; mt < 4; ++mt)
#pragma unroll
                for (int nt = 0; nt < 4; ++nt)
                    acc[mt][nt] = __builtin_amdgcn_mfma_f32_16x16x32_bf16(af[mt], bfr[nt], acc[mt][nt], 0, 0, 0);
        }
    }

    // epilogue: C/D layout row = quad*4+reg (m), col = l15 (n)
#pragma unroll
    for (int mt = 0; mt < 4; ++mt) {
        int mbase = m0 + wm + mt * 16 + quad * 4;
        int b = mbase >> 11;
        int s = mbase & 2047;
#pragma unroll
        for (int nt = 0; nt < 4; ++nt) {
            int gn = n0 + wn + nt * 16 + l15;
            int h = gn >> 6, d = gn & 63;
            if (!vtrans) {
                size_t base = ((size_t)((b * HEADS + h) * SEQ + s)) * HDIM + d;
#pragma unroll
                for (int r = 0; r < 4; ++r)
                    Out[base + (size_t)r * HDIM] = bf16r(acc[mt][nt][r] * scale);
            } else {
                size_t base = ((size_t)((b * HEADS + h) * HDIM + d)) * SEQ + s;
                ushort4v o;
                o.x = bf16r(acc[mt][nt][0]);
                o.y = bf16r(acc[mt][nt][1]);
                o.z = bf16r(acc[mt][nt][2]);
                o.w = bf16r(acc[mt][nt][3]);
                *(ushort4v*)(Out + base) = o;
            }
        }
    }
}

// ---------- Kernel 3: flash attention (r3 configuration, best measured 96.6us) ----------
// BQ=256: each of 4 waves owns 64 q-rows (mt=0..3). K/V fragments reused across
// 4 mt. Single-buffered K/V (55.3KB LDS -> 2 blocks/CU), register prefetch of
// next chunk, 2 barriers/chunk. Pad-72 rows. r4/r5 lessons: LDS>64KB kills
// residency (1 block/CU); V-direct-from-L2 + stride-4-row swizzle both regress.
// Key permutation trick: QK MFMA nt reads K-row l15*4+nt, lane (quad,l15) holds
// scores for keys {4*l15..4*l15+3}; PV sums keys in true order from Vsm, so the
// permutation cancels.
#define BQ  256
#define BKC 64

__global__ __launch_bounds__(256) void attn_kernel(
    const unsigned short* __restrict__ Q,    // [B][H][S][64] bf16, pre-scaled by 0.125*log2(e)
    const unsigned short* __restrict__ K,    // [B][H][S][64] bf16
    const unsigned short* __restrict__ Vt,   // [B][H][64][S] bf16
    float* __restrict__ Out)                 // [B][S][1024] fp32
{
    __shared__ __align__(16) unsigned short Ksm[BKC][72];
    __shared__ __align__(16) unsigned short Vsm[HDIM][72];
    __shared__ __align__(16) unsigned short Psm[4][64][72];

    int t = threadIdx.x;
    int wave = t >> 6, lane = t & 63, l15 = lane & 15, quad = lane >> 4;
    int L = blockIdx.x;
    int bh = L & 63;
    int b = bh >> 4, h = bh & 15;
    int q0 = (L >> 6) * BQ;

    const unsigned short* Qbh = Q + (size_t)bh * SEQ * HDIM;
    const unsigned short* Kbh = K + (size_t)bh * SEQ * HDIM;
    const unsigned short* Vbh = Vt + (size_t)bh * HDIM * SEQ;

    short8 qf[4][2];
#pragma unroll
    for (int mt = 0; mt < 4; ++mt) {
        int qr = q0 + wave * 64 + mt * 16 + l15;
        qf[mt][0] = *(const short8*)(Qbh + (size_t)qr * HDIM + quad * 8);
        qf[mt][1] = *(const short8*)(Qbh + (size_t)qr * HDIM + 32 + quad * 8);
    }

    float lsum[4][4];
    float4v acc_o[4][4];
#pragma unroll
    for (int mt = 0; mt < 4; ++mt) {
#pragma unroll
        for (int r = 0; r < 4; ++r) lsum[mt][r] = 0.f;
#pragma unroll
        for (int dtt = 0; dtt < 4; ++dtt) acc_o[mt][dtt] = (float4v){0.f, 0.f, 0.f, 0.f};
    }

    int srow = t >> 2;            // 0..63
    int sseg = (t & 3) * 16;
    const unsigned short* kptr = Kbh + (size_t)srow * HDIM + sseg;
    const unsigned short* vptr = Vbh + (size_t)srow * SEQ + sseg;

    // prefetch chunk 0 into registers
    short8 kv0 = *(const short8*)(kptr);
    short8 kv1 = *(const short8*)(kptr + 8);
    short8 kv2 = *(const short8*)(vptr);
    short8 kv3 = *(const short8*)(vptr + 8);

    for (int kc = 0; kc < SEQ; kc += BKC) {
        __syncthreads();
        *(short8*)&Ksm[srow][sseg]     = kv0;
        *(short8*)&Ksm[srow][sseg + 8] = kv1;
        *(short8*)&Vsm[srow][sseg]     = kv2;
        *(short8*)&Vsm[srow][sseg + 8] = kv3;
        __syncthreads();

        int kn = kc + BKC;
        if (kn < SEQ) {   // prefetch next chunk; latency hidden under this chunk's compute
            kv0 = *(const short8*)(kptr + (size_t)kn * HDIM);
            kv1 = *(const short8*)(kptr + (size_t)kn * HDIM + 8);
            kv2 = *(const short8*)(vptr + kn);
            kv3 = *(const short8*)(vptr + kn + 8);
        }

        // K fragments hoisted once per chunk, reused by all 4 mt
        short8 kf[4][2];
#pragma unroll
        for (int nt = 0; nt < 4; ++nt) {
            kf[nt][0] = *(const short8*)&Ksm[l15 * 4 + nt][quad * 8];
            kf[nt][1] = *(const short8*)&Ksm[l15 * 4 + nt][32 + quad * 8];
        }

        // per-mt: S = Q K^T then softmax+P-write (keeps sc live range at 16 VGPR)
#pragma unroll
        for (int mt = 0; mt < 4; ++mt) {
            float4v sc[4];
#pragma unroll
            for (int nt = 0; nt < 4; ++nt) sc[nt] = (float4v){0.f, 0.f, 0.f, 0.f};
            __builtin_amdgcn_s_setprio(1);
#pragma unroll
            for (int nt = 0; nt < 4; ++nt) {
                sc[nt] = __builtin_amdgcn_mfma_f32_16x16x32_bf16(qf[mt][0], kf[nt][0], sc[nt], 0, 0, 0);
                sc[nt] = __builtin_amdgcn_mfma_f32_16x16x32_bf16(qf[mt][1], kf[nt][1], sc[nt], 0, 0, 0);
            }
            __builtin_amdgcn_s_setprio(0);

            // fixed-max softmax: p = exp2(s); lane's 4 nt-values are keys 4*l15..+3.
#pragma unroll
            for (int r = 0; r < 4; ++r) {
                float p0 = __builtin_amdgcn_exp2f(sc[0][r]);
                float p1 = __builtin_amdgcn_exp2f(sc[1][r]);
                float p2 = __builtin_amdgcn_exp2f(sc[2][r]);
                float p3 = __builtin_amdgcn_exp2f(sc[3][r]);
                lsum[mt][r] += (p0 + p1) + (p2 + p3);
                int row = mt * 16 + quad * 4 + r;
                int2v pw;
                pw.x = (int)cvt_pk_bf16(p0, p1);
                pw.y = (int)cvt_pk_bf16(p2, p3);
                *(int2v*)&Psm[wave][row][l15 * 4] = pw;
            }
        }

        // PV: O += P V  (Psm wave-private; lgkmcnt covers the RAW)
        __builtin_amdgcn_s_setprio(1);
#pragma unroll
        for (int kseg = 0; kseg < 2; ++kseg) {
            short8 pf[4], vf[4];
#pragma unroll
            for (int mt = 0; mt < 4; ++mt)
                pf[mt] = *(const short8*)&Psm[wave][mt * 16 + l15][kseg * 32 + quad * 8];
#pragma unroll
            for (int dtt = 0; dtt < 4; ++dtt)
                vf[dtt] = *(const short8*)&Vsm[dtt * 16 + l15][kseg * 32 + quad * 8];
#pragma unroll
            for (int mt = 0; mt < 4; ++mt)
#pragma unroll
                for (int dtt = 0; dtt < 4; ++dtt)
                    acc_o[mt][dtt] = __builtin_amdgcn_mfma_f32_16x16x32_bf16(pf[mt], vf[dtt], acc_o[mt][dtt], 0, 0, 0);
        }
        __builtin_amdgcn_s_setprio(0);
    }

#pragma unroll
    for (int mt = 0; mt < 4; ++mt)
#pragma unroll
        for (int r = 0; r < 4; ++r) {
            float l = lsum[mt][r];
            l += __shfl_xor(l, 1);
            l += __shfl_xor(l, 2);
            l += __shfl_xor(l, 4);
            l += __shfl_xor(l, 8);
            float inv = 1.0f / l;
            int qrow = q0 + wave * 64 + mt * 16 + quad * 4 + r;
            size_t base = ((size_t)(b * SEQ + qrow)) * NDIM + h * HDIM;
#pragma unroll
            for (int dtt = 0; dtt < 4; ++dtt)
                Out[base + dtt * 16 + l15] = acc_o[mt][dtt][r] * inv;
        }
}

extern "C" void kernel_launch(void* const* d_in, const int* in_sizes, int n_in,
                              void* d_out, int out_size, void* d_ws, size_t ws_size,
                              hipStream_t stream)
{
    const float* q_in = (const float*)d_in[0];
    const float* k_in = (const float*)d_in[1];
    const float* v_in = (const float*)d_in[2];
    const float* WQ = (const float*)d_in[3];
    const float* WK = (const float*)d_in[4];
    const float* WV = (const float*)d_in[5];
    float* out = (float*)d_out;

    unsigned short* ws = (unsigned short*)d_ws;
    size_t wsz = (size_t)NDIM * NDIM;
    size_t psz = (size_t)MTOT * NDIM;
    unsigned short* Tq = ws;
    unsigned short* Tk = Tq + wsz;
    unsigned short* Tv = Tk + wsz;
    unsigned short* Qp = Tv + wsz;
    unsigned short* Kp = Qp + psz;
    unsigned short* Vp = Kp + psz;
    unsigned short* Xvc = Vp + psz;

    // Xq/Xk bf16 scratch lives in d_out (32MB, exactly 2*psz shorts); consumed
    // by proj_gemm before attn_kernel writes Out. Xv in workspace (r2-proven).
    unsigned short* Xqc = (unsigned short*)d_out;
    unsigned short* Xkc = Xqc + psz;

    cast_x<<<dim3(MTOT * NDIM / (256 * 8), 1, 3), 256, 0, stream>>>(
        q_in, k_in, v_in, Xqc, Xkc, Xvc);
    cast_transpose_w<<<dim3(16, 16, 3), 256, 0, stream>>>(WQ, WK, WV, Tq, Tk, Tv);
    proj_gemm<<<dim3(MTOT / BM, NDIM / BN, 3), 256, 0, stream>>>(
        Xqc, Xkc, Xvc, Tq, Tk, Tv, Qp, Kp, Vp, 0.125f * 1.44269504088896f);
    attn_kernel<<<dim3(SEQ / BQ * BATCH * HEADS), 256, 0, stream>>>(Qp, Kp, Vp, out);
}